// Round 19
// baseline (60.628 us; speedup 1.0000x reference)
//
#include <hip/hip_runtime.h>
#include <math.h>

#ifndef M_PI
#define M_PI 3.14159265358979323846
#endif

#define BATCHES 256
#define S_LEN   131072

// r19: CROSS-SEGMENT SOFTWARE PIPELINE. One block owns TWO adjacent segments
// A,B of a row. Mechanism: r12-r18 plateau (57-59us, 7 null levers, both
// pipes ~55%) is phase-lockstep duty-cycling -- all blocks read in P1, idle
// HBM in scan, write in P3. This schedule interleaves the streams:
//   P1(A) | bar | issue x(B) loads -> scan(A)   [B reads fill scan's HBM gap]
//   | bar | P3a(A), P1compute(B), P3b(A)        [no new traffic]
//   | bar | P3c(A) nt-writes + scan(B)          [A writes drain during scan]
//   | bar | P3(B)
// Bonus: scan(A) lane-63 final state = EXACT entry of B -> B needs no warmup
// (warmup overhead 18.75% -> 9.4%) and is exact (no truncation).
// A's warmup: 48 chunks (768 samples), truncation ~2.8e-3 vs thr 2.03e-2
// (measured absmax 0.0039 across r12-r18).
//
// Kept from r12-r18: CCH=16, 320-thread block (wave 4 = warmup), block-local
// Kogge-Stone affine scan, homogeneous correction y=y_zs+c1*H(t)+c2*H(t-1),
// szs in registers (16 VGPR), b128 staging, coalesced nt stores, __sinf.
#define TPB   320
#define MAINT 256
#define CCH   16
#define SEGS  32                      // segments per row
#define SEG_SAMPS (MAINT * CCH)       // 4096
#define PAIRS (SEGS / 2)              // 16 block-pairs per row
#define WCH   48                      // warmup chunks (segment A only)

#define OBSTR   20                    // staging stride (16 samples + 4 pad)
#define STG_OFF 0                     // 256*20 = 5120 floats
#define SC1_OFF 5120                  // scan A: 6 arrays x 305
#define SC1_STR 305
#define SC2_OFF 6950                  // scan B: 6 arrays x 257
#define SC2_STR 257
#define H_OFF   8492                  // 3 bands x 16 (16B-aligned: 8492*4%16==0)
#define E0_OFF  8540                  // 6 floats: exact entry state of B per band
#define LDSF    8548                  // 34192 B -> 4 blocks/CU

typedef float v4f __attribute__((ext_vector_type(4)));

__device__ __forceinline__ void compute_coeffs(float level_in, float b0[3], float na1[3], float na2[3]) {
    const float FD[3] = {270.0f, 800.0f, 2300.0f};
    const float FN[3] = {500.0f, 1500.0f, 2500.0f};
    const float FB[3] = {730.0f, 2100.0f, 3000.0f};
    float level = fminf(fmaxf(level_in, 0.0f), 1.0f);
    float t_low  = fminf(fmaxf(level * 2.0f, 0.0f), 1.0f);
    float t_high = fminf(fmaxf((level - 0.5f) * 2.0f, 0.0f), 1.0f);
    bool hi = (level >= 0.5f);
    const float W0 = (float)(2.0 * M_PI / 16000.0);
    #pragma unroll
    for (int k = 0; k < 3; ++k) {
        float f, q;
        if (hi) { f = (1.0f - t_high) * FN[k] + t_high * FB[k];
                  q = (1.0f - t_high) * 8.0f  + t_high * 12.0f; }
        else    { f = (1.0f - t_low) * FD[k] + t_low * FN[k];
                  q = (1.0f - t_low) * 5.0f  + t_low * 8.0f; }
        float omega = W0 * f;
        float sn = __sinf(omega), cs = __cosf(omega);   // native v_sin/v_cos
        float alpha = sn / (2.0f * fmaxf(q, 0.5f));
        float a0 = 1.0f + alpha;
        b0[k]  = alpha / a0;             // b2 == -b0 exactly
        na1[k] = (2.0f * cs) / a0;       // -a1
        na2[k] = -((1.0f - alpha) / a0); // -a2
    }
}

#define STEP3(XT, XTM2, SUMV)                                                    \
    {                                                                            \
        float d = (XT) - (XTM2);                                                 \
        float e0 = fmaf(b0[0], d, na2[0] * y2[0]);                               \
        float e1 = fmaf(b0[1], d, na2[1] * y2[1]);                               \
        float e2 = fmaf(b0[2], d, na2[2] * y2[2]);                               \
        float yy0 = fmaf(na1[0], y1[0], e0);                                     \
        float yy1 = fmaf(na1[1], y1[1], e1);                                     \
        float yy2 = fmaf(na1[2], y1[2], e2);                                     \
        y2[0] = y1[0]; y1[0] = yy0;                                              \
        y2[1] = y1[1]; y1[1] = yy1;                                              \
        y2[2] = y1[2]; y1[2] = yy2;                                              \
        SUMV = (yy0 + yy1 + yy2);                                                \
    }

// 2x2 matrix multiply: R = X * Y
#define MMUL(R00,R01,R10,R11, X00,X01,X10,X11, Y00,Y01,Y10,Y11)                  \
    {                                                                            \
        R00 = X00*Y00 + X01*Y10; R01 = X00*Y01 + X01*Y11;                        \
        R10 = X10*Y00 + X11*Y10; R11 = X10*Y01 + X11*Y11;                        \
    }

__global__ __launch_bounds__(TPB, 2)
void formant_pair(const float* __restrict__ x, const float* __restrict__ lvl,
                  float* __restrict__ out)
{
    __shared__ float lds[LDSF];

    const int tid  = threadIdx.x;
    const int row  = blockIdx.x >> 4;
    const int pair = blockIdx.x & (PAIRS - 1);

    float b0[3], na1[3], na2[3];
    compute_coeffs(lvl[row], b0, na1, na2);

    const float* xrow = x + (size_t)row * S_LEN;
    const size_t baseA = (size_t)(2 * pair) * SEG_SAMPS;
    const size_t baseB = baseA + SEG_SAMPS;

    float4 szsA[4];   // zero-state band-sum of A, registers

    // -------- P1(A): main chunks (threads 0..255) + warmup on wave 4 --------
    if (tid < MAINT) {
        const float* xc = xrow + baseA + (size_t)tid * CCH;
        float xm1 = 0.f, xm2 = 0.f;
        if (pair > 0 || tid > 0) { float2 t2 = *(const float2*)(xc - 2); xm2 = t2.x; xm1 = t2.y; }
        float y1[3] = {0.f,0.f,0.f}, y2[3] = {0.f,0.f,0.f};
        const float4* xv = (const float4*)xc;
        float4 buf[4];
        #pragma unroll
        for (int j = 0; j < 4; ++j) buf[j] = xv[j];
        #pragma unroll
        for (int i = 0; i < 4; ++i) {
            float4 q = buf[i];
            float4 o;
            STEP3(q.x, xm2, o.x)
            STEP3(q.y, xm1, o.y)
            STEP3(q.z, q.x, o.z)
            STEP3(q.w, q.y, o.w)
            xm2 = q.z; xm1 = q.w;
            szsA[i] = o;
        }
        lds[SC1_OFF + 0*SC1_STR + WCH + tid] = y1[0];
        lds[SC1_OFF + 1*SC1_STR + WCH + tid] = y2[0];
        lds[SC1_OFF + 2*SC1_STR + WCH + tid] = y1[1];
        lds[SC1_OFF + 3*SC1_STR + WCH + tid] = y2[1];
        lds[SC1_OFF + 4*SC1_STR + WCH + tid] = y1[2];
        lds[SC1_OFF + 5*SC1_STR + WCH + tid] = y2[2];
    } else if (tid < MAINT + WCH) {
        const int wid = tid - MAINT;
        if (pair == 0) {
            #pragma unroll
            for (int e = 0; e < 6; ++e) lds[SC1_OFF + e*SC1_STR + wid] = 0.f;   // exact
        } else {
            const float* xw = xrow + baseA - (size_t)(WCH * CCH) + (size_t)wid * CCH;
            float2 t2 = *(const float2*)(xw - 2);
            float y1[3] = {0.f,0.f,0.f}, y2[3] = {0.f,0.f,0.f};
            float p2 = t2.x, p1 = t2.y, dummy;
            const float4* xv = (const float4*)xw;
            float4 buf[4];
            #pragma unroll
            for (int j = 0; j < 4; ++j) buf[j] = xv[j];
            #pragma unroll
            for (int i = 0; i < 4; ++i) {
                float4 q = buf[i];
                STEP3(q.x, p2, dummy)
                STEP3(q.y, p1, dummy)
                STEP3(q.z, q.x, dummy)
                STEP3(q.w, q.y, dummy)
                p2 = q.z; p1 = q.w;
            }
            (void)dummy;
            lds[SC1_OFF + 0*SC1_STR + wid] = y1[0];
            lds[SC1_OFF + 1*SC1_STR + wid] = y2[0];
            lds[SC1_OFF + 2*SC1_STR + wid] = y1[1];
            lds[SC1_OFF + 3*SC1_STR + wid] = y2[1];
            lds[SC1_OFF + 4*SC1_STR + wid] = y1[2];
            lds[SC1_OFF + 5*SC1_STR + wid] = y2[2];
        }
    }
    __syncthreads();   // bar1

    // -------- issue x(B) loads EARLY: they fly during scan(A) --------
    float4 bufB[4];
    float xmB1 = 0.f, xmB2 = 0.f;
    if (tid < MAINT) {
        const float* xcB = xrow + baseB + (size_t)tid * CCH;
        const float4* xvB = (const float4*)xcB;
        #pragma unroll
        for (int j = 0; j < 4; ++j) bufB[j] = xvB[j];
        float2 t2 = *(const float2*)(xcB - 2); xmB2 = t2.x; xmB1 = t2.y;
    }

    // -------- scan(A): waves 0-2 over 304 states; store H table + exact e0(B) ----
    {
        const int wv = tid >> 6, ln = tid & 63;
        if (wv < 3) {
            const float A1 = na1[wv], A2 = na2[wv];
            float hm1 = 1.f, hm2 = 0.f, hm3 = 0.f;   // H(-1)=1, H(-2)=0
            for (int i = 0; i < CCH; ++i) {
                float h = fmaf(A1, hm1, A2 * hm2);
                hm3 = hm2; hm2 = hm1; hm1 = h;
                if (ln == 0) lds[H_OFF + wv * CCH + i] = h;
            }
            const float H00 = hm1, H01 = A2 * hm2;
            const float H10 = hm2, H11 = A2 * hm3;

            float* z1p = lds + SC1_OFF + (2*wv) * SC1_STR;
            float* z2p = lds + SC1_OFF + (2*wv + 1) * SC1_STR;

            const int cnt = (ln < 48) ? 5 : 4;
            const int beg = (ln < 48) ? 5 * ln : 240 + 4 * (ln - 48);

            float s1 = 0.f, s2 = 0.f;
            for (int j = 0; j < cnt; ++j) {
                float z1 = z1p[beg + j], z2 = z2p[beg + j];
                float n1 = z1 + H00 * s1 + H01 * s2;
                float n2 = z2 + H10 * s1 + H11 * s2;
                s1 = n1; s2 = n2;
            }
            float B00,B01,B10,B11, C00,C01,C10,C11;
            MMUL(B00,B01,B10,B11, H00,H01,H10,H11, H00,H01,H10,H11)   // H^2
            MMUL(C00,C01,C10,C11, B00,B01,B10,B11, B00,B01,B10,B11)   // H^4
            float A00 = C00, A01 = C01, A10 = C10, A11 = C11;
            if (cnt == 5) {
                float D00,D01,D10,D11;
                MMUL(D00,D01,D10,D11, C00,C01,C10,C11, H00,H01,H10,H11)
                A00 = D00; A01 = D01; A10 = D10; A11 = D11;
            }
            float bb1 = s1, bb2 = s2;
            for (int d = 1; d < 64; d <<= 1) {
                float iA00 = __shfl_up(A00, d), iA01 = __shfl_up(A01, d);
                float iA10 = __shfl_up(A10, d), iA11 = __shfl_up(A11, d);
                float ib1  = __shfl_up(bb1, d), ib2  = __shfl_up(bb2, d);
                if (ln >= d) {
                    float nb1 = A00 * ib1 + A01 * ib2 + bb1;
                    float nb2 = A10 * ib1 + A11 * ib2 + bb2;
                    float n00, n01, n10, n11;
                    MMUL(n00,n01,n10,n11, A00,A01,A10,A11, iA00,iA01,iA10,iA11)
                    A00 = n00; A01 = n01; A10 = n10; A11 = n11;
                    bb1 = nb1; bb2 = nb2;
                }
            }
            float e1 = __shfl_up(bb1, 1), e2 = __shfl_up(bb2, 1);
            if (ln == 0) { e1 = 0.f; e2 = 0.f; }

            // replay: overwrite z with corrected chunk-ENTRY states
            s1 = e1; s2 = e2;
            for (int j = 0; j < cnt; ++j) {
                int w = beg + j;
                float z1 = z1p[w], z2 = z2p[w];
                z1p[w] = s1; z2p[w] = s2;
                float n1 = z1 + H00 * s1 + H01 * s2;
                float n2 = z2 + H10 * s1 + H11 * s2;
                s1 = n1; s2 = n2;
            }
            // lane 63's final state = EXACT entry state of segment B
            if (ln == 63) { lds[E0_OFF + 2*wv] = s1; lds[E0_OFF + 2*wv + 1] = s2; }
        }
    }
    __syncthreads();   // bar2

    // -------- P3a(A) + P1compute(B) + P3b(A) (no global traffic except latent B) ----
    float4 szsB[4];
    if (tid < MAINT) {
        float c1A[3], c2A[3];
        #pragma unroll
        for (int k = 0; k < 3; ++k) {
            c1A[k] = lds[SC1_OFF + (2*k) * SC1_STR + WCH + tid];
            c2A[k] = na2[k] * lds[SC1_OFF + (2*k + 1) * SC1_STR + WCH + tid];
        }
        // P1-compute(B): zero-state from prefetched registers
        {
            float y1[3] = {0.f,0.f,0.f}, y2[3] = {0.f,0.f,0.f};
            float p2 = xmB2, p1 = xmB1;
            #pragma unroll
            for (int i = 0; i < 4; ++i) {
                float4 q = bufB[i];
                float4 o;
                STEP3(q.x, p2, o.x)
                STEP3(q.y, p1, o.y)
                STEP3(q.z, q.x, o.z)
                STEP3(q.w, q.y, o.w)
                p2 = q.z; p1 = q.w;
                szsB[i] = o;
            }
            lds[SC2_OFF + 0*SC2_STR + tid] = y1[0];
            lds[SC2_OFF + 1*SC2_STR + tid] = y2[0];
            lds[SC2_OFF + 2*SC2_STR + tid] = y1[1];
            lds[SC2_OFF + 3*SC2_STR + tid] = y2[1];
            lds[SC2_OFF + 4*SC2_STR + tid] = y1[2];
            lds[SC2_OFF + 5*SC2_STR + tid] = y2[2];
        }
        // P3b(A): correct own chunk, stage as b128
        {
            const float is3 = 0.57735026918962576f;
            float* myst = lds + STG_OFF + tid * OBSTR;
            float hp[3] = {1.f, 1.f, 1.f};
            #pragma unroll
            for (int i = 0; i < 4; ++i) {
                float4 s = szsA[i];
                float o0 = s.x, o1 = s.y, o2 = s.z, o3 = s.w;
                #pragma unroll
                for (int k = 0; k < 3; ++k) {
                    const float4 hv = *(const float4*)&lds[H_OFF + k * CCH + 4 * i];
                    o0 = fmaf(c1A[k], hv.x, fmaf(c2A[k], hp[k], o0));
                    o1 = fmaf(c1A[k], hv.y, fmaf(c2A[k], hv.x,  o1));
                    o2 = fmaf(c1A[k], hv.z, fmaf(c2A[k], hv.y,  o2));
                    o3 = fmaf(c1A[k], hv.w, fmaf(c2A[k], hv.z,  o3));
                    hp[k] = hv.w;
                }
                v4f o = { o0 * is3, o1 * is3, o2 * is3, o3 * is3 };
                *(v4f*)(myst + 4 * i) = o;
            }
        }
    }
    __syncthreads();   // bar3

    // -------- P3c(A) nt-writes (drain during scan(B)) --------
    {
        float* obase = out + (size_t)row * S_LEN + baseA;
        #pragma unroll
        for (int j = 0; j < 3; ++j) {
            const int f = j * TPB + tid;
            const v4f o = *(const v4f*)(lds + STG_OFF + (f >> 2) * OBSTR + (f & 3) * 4);
            __builtin_nontemporal_store(o, (v4f*)(obase + (size_t)f * 4));
        }
        if (tid < 1024 - 3 * TPB) {
            const int f = 3 * TPB + tid;
            const v4f o = *(const v4f*)(lds + STG_OFF + (f >> 2) * OBSTR + (f & 3) * 4);
            __builtin_nontemporal_store(o, (v4f*)(obase + (size_t)f * 4));
        }
    }

    // -------- scan(B): waves 0-2 over 256 states, seeded with exact e0 --------
    {
        const int wv = tid >> 6, ln = tid & 63;
        if (wv < 3) {
            const float A1 = na1[wv], A2 = na2[wv];
            float hm1 = 1.f, hm2 = 0.f, hm3 = 0.f;
            for (int i = 0; i < CCH; ++i) {
                float h = fmaf(A1, hm1, A2 * hm2);
                hm3 = hm2; hm2 = hm1; hm1 = h;
            }
            const float H00 = hm1, H01 = A2 * hm2;
            const float H10 = hm2, H11 = A2 * hm3;

            float* z1p = lds + SC2_OFF + (2*wv) * SC2_STR;
            float* z2p = lds + SC2_OFF + (2*wv + 1) * SC2_STR;

            const float e01 = lds[E0_OFF + 2*wv], e02 = lds[E0_OFF + 2*wv + 1];
            const int beg = 4 * ln;

            float s1 = (ln == 0) ? e01 : 0.f;
            float s2 = (ln == 0) ? e02 : 0.f;
            #pragma unroll
            for (int j = 0; j < 4; ++j) {
                float z1 = z1p[beg + j], z2 = z2p[beg + j];
                float n1 = z1 + H00 * s1 + H01 * s2;
                float n2 = z2 + H10 * s1 + H11 * s2;
                s1 = n1; s2 = n2;
            }
            float B00,B01,B10,B11;
            MMUL(B00,B01,B10,B11, H00,H01,H10,H11, H00,H01,H10,H11)   // H^2
            float A00,A01,A10,A11;
            MMUL(A00,A01,A10,A11, B00,B01,B10,B11, B00,B01,B10,B11)   // H^4
            float bb1 = s1, bb2 = s2;
            for (int d = 1; d < 64; d <<= 1) {
                float iA00 = __shfl_up(A00, d), iA01 = __shfl_up(A01, d);
                float iA10 = __shfl_up(A10, d), iA11 = __shfl_up(A11, d);
                float ib1  = __shfl_up(bb1, d), ib2  = __shfl_up(bb2, d);
                if (ln >= d) {
                    float nb1 = A00 * ib1 + A01 * ib2 + bb1;
                    float nb2 = A10 * ib1 + A11 * ib2 + bb2;
                    float n00, n01, n10, n11;
                    MMUL(n00,n01,n10,n11, A00,A01,A10,A11, iA00,iA01,iA10,iA11)
                    A00 = n00; A01 = n01; A10 = n10; A11 = n11;
                    bb1 = nb1; bb2 = nb2;
                }
            }
            float e1 = __shfl_up(bb1, 1), e2 = __shfl_up(bb2, 1);
            if (ln == 0) { e1 = e01; e2 = e02; }

            s1 = e1; s2 = e2;
            #pragma unroll
            for (int j = 0; j < 4; ++j) {
                int w = beg + j;
                float z1 = z1p[w], z2 = z2p[w];
                z1p[w] = s1; z2p[w] = s2;
                float n1 = z1 + H00 * s1 + H01 * s2;
                float n2 = z2 + H10 * s1 + H11 * s2;
                s1 = n1; s2 = n2;
            }
        }
    }
    __syncthreads();   // bar4

    // -------- P3(B): correct + stage --------
    if (tid < MAINT) {
        float c1B[3], c2B[3];
        #pragma unroll
        for (int k = 0; k < 3; ++k) {
            c1B[k] = lds[SC2_OFF + (2*k) * SC2_STR + tid];
            c2B[k] = na2[k] * lds[SC2_OFF + (2*k + 1) * SC2_STR + tid];
        }
        const float is3 = 0.57735026918962576f;
        float* myst = lds + STG_OFF + tid * OBSTR;
        float hp[3] = {1.f, 1.f, 1.f};
        #pragma unroll
        for (int i = 0; i < 4; ++i) {
            float4 s = szsB[i];
            float o0 = s.x, o1 = s.y, o2 = s.z, o3 = s.w;
            #pragma unroll
            for (int k = 0; k < 3; ++k) {
                const float4 hv = *(const float4*)&lds[H_OFF + k * CCH + 4 * i];
                o0 = fmaf(c1B[k], hv.x, fmaf(c2B[k], hp[k], o0));
                o1 = fmaf(c1B[k], hv.y, fmaf(c2B[k], hv.x,  o1));
                o2 = fmaf(c1B[k], hv.z, fmaf(c2B[k], hv.y,  o2));
                o3 = fmaf(c1B[k], hv.w, fmaf(c2B[k], hv.z,  o3));
                hp[k] = hv.w;
            }
            v4f o = { o0 * is3, o1 * is3, o2 * is3, o3 * is3 };
            *(v4f*)(myst + 4 * i) = o;
        }
    }
    __syncthreads();   // bar5

    // -------- P3c(B): coalesced nt stores --------
    {
        float* obase = out + (size_t)row * S_LEN + baseB;
        #pragma unroll
        for (int j = 0; j < 3; ++j) {
            const int f = j * TPB + tid;
            const v4f o = *(const v4f*)(lds + STG_OFF + (f >> 2) * OBSTR + (f & 3) * 4);
            __builtin_nontemporal_store(o, (v4f*)(obase + (size_t)f * 4));
        }
        if (tid < 1024 - 3 * TPB) {
            const int f = 3 * TPB + tid;
            const v4f o = *(const v4f*)(lds + STG_OFF + (f >> 2) * OBSTR + (f & 3) * 4);
            __builtin_nontemporal_store(o, (v4f*)(obase + (size_t)f * 4));
        }
    }
}

extern "C" void kernel_launch(void* const* d_in, const int* in_sizes, int n_in,
                              void* d_out, int out_size, void* d_ws, size_t ws_size,
                              hipStream_t stream) {
    const float* audio = (const float*)d_in[0];
    const float* level = (const float*)d_in[1];
    float* out = (float*)d_out;
    (void)in_sizes; (void)n_in; (void)d_ws; (void)ws_size; (void)out_size;

    formant_pair<<<BATCHES * PAIRS, TPB, 0, stream>>>(audio, level, out);
}

// Round 20
// 58.084 us; speedup vs baseline: 1.0438x; 1.0438x over previous
//
#include <hip/hip_runtime.h>
#include <math.h>

#ifndef M_PI
#define M_PI 3.14159265358979323846
#endif

#define BATCHES 256
#define S_LEN   131072

// FINAL (r20 = r18 revert, best measured: 57.0us).
// r19's cross-segment pipeline regressed (60.6us) -> pre-registered read:
// plateau is structural. Arithmetic: 265MB min traffic / ~5TB/s mixed-stream
// ~= 53us floor; + ~8% un-overlapped serial-FMA latency residue = ~57us.
// 8 orthogonal levers measured null/negative at this plateau (r12-r19).
//
// Structure: one kernel, independent blocks, truncated-warmup linear
// recurrence. Block = 320 thr (5 waves): threads 0..255 own 16-sample
// chunks (4096-sample segment), wave 4 computes 48 warmup chunks (768
// samples) concurrently. Worst pole r=0.98948 -> truncation ~2.8e-3 vs
// threshold 2.03e-2 (measured absmax 0.0039). Block-local Kogge-Stone
// affine scan (waves 0..2, 304 states); phase 3 homogeneous correction
// y(t)=y_zs(t)+c1*H(t)+c2*H(t-1) with szs in registers (16 VGPR), c1/c2
// loaded once, H broadcast b128, b128 staging (OBSTR=20), coalesced
// non-temporal stores; 4 barriers; __sinf coeffs; VGPR 28, LDS 20.7KB.
#define TPB   320
#define MAINT 256
#define CCH   16
#define SEGS  32                      // segments per row
#define SEG_SAMPS (MAINT * CCH)       // 4096
#define WCH   48                      // warmup chunks (768 samples)
#define OBSTR 20                      // staging stride (16 samples + 4 pad; 16B-aligned b128)
#define SCAN_STR 305                  // per-array scan stride (304 + 1 pad); scan at offset 0
#define H_OFF 5120                    // H table after staging region (256*20)
#define LDSF  (H_OFF + 3 * CCH)       // 5168 floats = 20672 B

typedef float v4f __attribute__((ext_vector_type(4)));

__device__ __forceinline__ void compute_coeffs(float level_in, float b0[3], float na1[3], float na2[3]) {
    const float FD[3] = {270.0f, 800.0f, 2300.0f};
    const float FN[3] = {500.0f, 1500.0f, 2500.0f};
    const float FB[3] = {730.0f, 2100.0f, 3000.0f};
    float level = fminf(fmaxf(level_in, 0.0f), 1.0f);
    float t_low  = fminf(fmaxf(level * 2.0f, 0.0f), 1.0f);
    float t_high = fminf(fmaxf((level - 0.5f) * 2.0f, 0.0f), 1.0f);
    bool hi = (level >= 0.5f);
    const float W0 = (float)(2.0 * M_PI / 16000.0);
    #pragma unroll
    for (int k = 0; k < 3; ++k) {
        float f, q;
        if (hi) { f = (1.0f - t_high) * FN[k] + t_high * FB[k];
                  q = (1.0f - t_high) * 8.0f  + t_high * 12.0f; }
        else    { f = (1.0f - t_low) * FD[k] + t_low * FN[k];
                  q = (1.0f - t_low) * 5.0f  + t_low * 8.0f; }
        float omega = W0 * f;
        float sn = __sinf(omega), cs = __cosf(omega);   // native v_sin/v_cos
        float alpha = sn / (2.0f * fmaxf(q, 0.5f));
        float a0 = 1.0f + alpha;
        b0[k]  = alpha / a0;             // b2 == -b0 exactly
        na1[k] = (2.0f * cs) / a0;       // -a1
        na2[k] = -((1.0f - alpha) / a0); // -a2
    }
}

#define STEP3(XT, XTM2, SUMV)                                                    \
    {                                                                            \
        float d = (XT) - (XTM2);                                                 \
        float e0 = fmaf(b0[0], d, na2[0] * y2[0]);                               \
        float e1 = fmaf(b0[1], d, na2[1] * y2[1]);                               \
        float e2 = fmaf(b0[2], d, na2[2] * y2[2]);                               \
        float yy0 = fmaf(na1[0], y1[0], e0);                                     \
        float yy1 = fmaf(na1[1], y1[1], e1);                                     \
        float yy2 = fmaf(na1[2], y1[2], e2);                                     \
        y2[0] = y1[0]; y1[0] = yy0;                                              \
        y2[1] = y1[1]; y1[1] = yy1;                                              \
        y2[2] = y1[2]; y1[2] = yy2;                                              \
        SUMV = (yy0 + yy1 + yy2);                                                \
    }

// 2x2 matrix multiply: R = X * Y
#define MMUL(R00,R01,R10,R11, X00,X01,X10,X11, Y00,Y01,Y10,Y11)                  \
    {                                                                            \
        R00 = X00*Y00 + X01*Y10; R01 = X00*Y01 + X01*Y11;                        \
        R10 = X10*Y00 + X11*Y10; R11 = X10*Y01 + X11*Y11;                        \
    }

__global__ __launch_bounds__(TPB, 2)
void formant_onepass(const float* __restrict__ x, const float* __restrict__ lvl,
                     float* __restrict__ out)
{
    __shared__ float lds[LDSF];

    const int tid = threadIdx.x;
    const int row = blockIdx.x >> 5;
    const int seg = blockIdx.x & (SEGS - 1);

    float b0[3], na1[3], na2[3];
    compute_coeffs(lvl[row], b0, na1, na2);

    const float* xrow = x + (size_t)row * S_LEN;
    const size_t segBase = (size_t)seg * SEG_SAMPS;

    float4 szs[4];   // zero-state band-sum, 16 VGPR, live P1 -> P3b

    // -------- phase 1a: main-chunk zero-state, szs kept in registers --------
    if (tid < MAINT) {
        const float* xc = xrow + segBase + (size_t)tid * CCH;
        float xm1 = 0.f, xm2 = 0.f;
        if (seg > 0 || tid > 0) { float2 t2 = *(const float2*)(xc - 2); xm2 = t2.x; xm1 = t2.y; }
        float y1[3] = {0.f,0.f,0.f}, y2[3] = {0.f,0.f,0.f};
        const float4* xv = (const float4*)xc;
        float4 buf[4];
        #pragma unroll
        for (int j = 0; j < 4; ++j) buf[j] = xv[j];
        #pragma unroll
        for (int i = 0; i < 4; ++i) {
            float4 q = buf[i];
            float4 o;
            STEP3(q.x, xm2, o.x)
            STEP3(q.y, xm1, o.y)
            STEP3(q.z, q.x, o.z)
            STEP3(q.w, q.y, o.w)
            xm2 = q.z; xm1 = q.w;
            szs[i] = o;
        }
        // end-of-chunk states -> scan arrays (offset 0) at index WCH+tid
        lds[0*SCAN_STR + WCH + tid] = y1[0];
        lds[1*SCAN_STR + WCH + tid] = y2[0];
        lds[2*SCAN_STR + WCH + tid] = y1[1];
        lds[3*SCAN_STR + WCH + tid] = y2[1];
        lds[4*SCAN_STR + WCH + tid] = y1[2];
        lds[5*SCAN_STR + WCH + tid] = y2[2];
    }
    // -------- phase 1b: warmup chunks on DEDICATED wave 4 (threads 256..303) --------
    else if (tid < MAINT + WCH) {
        const int wid = tid - MAINT;
        if (seg == 0) {
            #pragma unroll
            for (int e = 0; e < 6; ++e) lds[e*SCAN_STR + wid] = 0.f;   // exact
        } else {
            const float* xw = xrow + segBase - (size_t)(WCH * CCH) + (size_t)wid * CCH;
            float2 t2 = *(const float2*)(xw - 2);
            float y1[3] = {0.f,0.f,0.f}, y2[3] = {0.f,0.f,0.f};
            float p2 = t2.x, p1 = t2.y, dummy;
            const float4* xv = (const float4*)xw;
            float4 buf[4];
            #pragma unroll
            for (int j = 0; j < 4; ++j) buf[j] = xv[j];
            #pragma unroll
            for (int i = 0; i < 4; ++i) {
                float4 q = buf[i];
                STEP3(q.x, p2, dummy)
                STEP3(q.y, p1, dummy)
                STEP3(q.z, q.x, dummy)
                STEP3(q.w, q.y, dummy)
                p2 = q.z; p1 = q.w;
            }
            (void)dummy;
            lds[0*SCAN_STR + wid] = y1[0];
            lds[1*SCAN_STR + wid] = y2[0];
            lds[2*SCAN_STR + wid] = y1[1];
            lds[3*SCAN_STR + wid] = y2[1];
            lds[4*SCAN_STR + wid] = y1[2];
            lds[5*SCAN_STR + wid] = y2[2];
        }
    }
    __syncthreads();

    // -------- phase 2: block-local affine scan over 304 chunk states + H table --------
    // waves 0..2; lanes 0..47 fold 5 chunks, lanes 48..63 fold 4 (48*5+16*4=304)
    {
        const int wv = tid >> 6, ln = tid & 63;
        if (wv < 3) {
            const float A1 = na1[wv], A2 = na2[wv];
            float hm1 = 1.f, hm2 = 0.f, hm3 = 0.f;   // H(-1)=1, H(-2)=0
            for (int i = 0; i < CCH; ++i) {
                float h = fmaf(A1, hm1, A2 * hm2);
                hm3 = hm2; hm2 = hm1; hm1 = h;
                if (ln == 0) lds[H_OFF + wv * CCH + i] = h;   // H(i)
            }
            const float H00 = hm1, H01 = A2 * hm2;
            const float H10 = hm2, H11 = A2 * hm3;

            float* z1p = lds + (2*wv) * SCAN_STR;
            float* z2p = lds + (2*wv + 1) * SCAN_STR;

            const int cnt = (ln < 48) ? 5 : 4;
            const int beg = (ln < 48) ? 5 * ln : 240 + 4 * (ln - 48);

            float s1 = 0.f, s2 = 0.f;
            for (int j = 0; j < cnt; ++j) {
                float z1 = z1p[beg + j], z2 = z2p[beg + j];
                float n1 = z1 + H00 * s1 + H01 * s2;
                float n2 = z2 + H10 * s1 + H11 * s2;
                s1 = n1; s2 = n2;
            }
            float B00,B01,B10,B11, C00,C01,C10,C11;
            MMUL(B00,B01,B10,B11, H00,H01,H10,H11, H00,H01,H10,H11)   // H^2
            MMUL(C00,C01,C10,C11, B00,B01,B10,B11, B00,B01,B10,B11)   // H^4
            float A00 = C00, A01 = C01, A10 = C10, A11 = C11;
            if (cnt == 5) {
                float D00,D01,D10,D11;
                MMUL(D00,D01,D10,D11, C00,C01,C10,C11, H00,H01,H10,H11)
                A00 = D00; A01 = D01; A10 = D10; A11 = D11;
            }
            float bb1 = s1, bb2 = s2;
            for (int d = 1; d < 64; d <<= 1) {
                float iA00 = __shfl_up(A00, d), iA01 = __shfl_up(A01, d);
                float iA10 = __shfl_up(A10, d), iA11 = __shfl_up(A11, d);
                float ib1  = __shfl_up(bb1, d), ib2  = __shfl_up(bb2, d);
                if (ln >= d) {
                    float nb1 = A00 * ib1 + A01 * ib2 + bb1;
                    float nb2 = A10 * ib1 + A11 * ib2 + bb2;
                    float n00, n01, n10, n11;
                    MMUL(n00,n01,n10,n11, A00,A01,A10,A11, iA00,iA01,iA10,iA11)
                    A00 = n00; A01 = n01; A10 = n10; A11 = n11;
                    bb1 = nb1; bb2 = nb2;
                }
            }
            float e1 = __shfl_up(bb1, 1), e2 = __shfl_up(bb2, 1);
            if (ln == 0) { e1 = 0.f; e2 = 0.f; }

            // replay: overwrite z with corrected chunk-ENTRY states (y[-1], y[-2])
            s1 = e1; s2 = e2;
            for (int j = 0; j < cnt; ++j) {
                int w = beg + j;
                float z1 = z1p[w], z2 = z2p[w];
                z1p[w] = s1; z2p[w] = s2;
                float n1 = z1 + H00 * s1 + H01 * s2;
                float n2 = z2 + H10 * s1 + H11 * s2;
                s1 = n1; s2 = n2;
            }
        }
    }
    __syncthreads();

    // -------- phase 3a: load correction coeffs ONCE (before staging aliases scan) ----
    float c1k[3], c2k[3];
    if (tid < MAINT) {
        #pragma unroll
        for (int k = 0; k < 3; ++k) {
            c1k[k] = lds[(2*k) * SCAN_STR + WCH + tid];
            c2k[k] = na2[k] * lds[(2*k + 1) * SCAN_STR + WCH + tid];
        }
    }
    __syncthreads();   // all c-reads done; staging may now overwrite scan region

    // -------- phase 3b: correct OWN chunk in registers; b128 store to staging ----
    if (tid < MAINT) {
        const float is3 = 0.57735026918962576f;   // 1/sqrt(3)
        float* myst = lds + tid * OBSTR;
        float hp[3] = {1.f, 1.f, 1.f};            // H(-1) = 1
        #pragma unroll
        for (int i = 0; i < 4; ++i) {
            float4 s = szs[i];
            float o0 = s.x, o1 = s.y, o2 = s.z, o3 = s.w;
            #pragma unroll
            for (int k = 0; k < 3; ++k) {
                const float4 hv = *(const float4*)&lds[H_OFF + k * CCH + 4 * i]; // broadcast
                o0 = fmaf(c1k[k], hv.x, fmaf(c2k[k], hp[k], o0));
                o1 = fmaf(c1k[k], hv.y, fmaf(c2k[k], hv.x,  o1));
                o2 = fmaf(c1k[k], hv.z, fmaf(c2k[k], hv.y,  o2));
                o3 = fmaf(c1k[k], hv.w, fmaf(c2k[k], hv.z,  o3));
                hp[k] = hv.w;
            }
            v4f o = { o0 * is3, o1 * is3, o2 * is3, o3 * is3 };
            *(v4f*)(myst + 4 * i) = o;            // ds_write_b128, 16B aligned
        }
    }
    __syncthreads();

    // -------- phase 3c: coalesced nt store (1024 float4 over 320 threads) --------
    {
        float* obase = out + (size_t)row * S_LEN + segBase;
        #pragma unroll
        for (int j = 0; j < 3; ++j) {
            const int f = j * TPB + tid;
            const v4f o = *(const v4f*)(lds + (f >> 2) * OBSTR + (f & 3) * 4);
            __builtin_nontemporal_store(o, (v4f*)(obase + (size_t)f * 4));
        }
        if (tid < 1024 - 3 * TPB) {               // tail: 64 float4s
            const int f = 3 * TPB + tid;
            const v4f o = *(const v4f*)(lds + (f >> 2) * OBSTR + (f & 3) * 4);
            __builtin_nontemporal_store(o, (v4f*)(obase + (size_t)f * 4));
        }
    }
}

extern "C" void kernel_launch(void* const* d_in, const int* in_sizes, int n_in,
                              void* d_out, int out_size, void* d_ws, size_t ws_size,
                              hipStream_t stream) {
    const float* audio = (const float*)d_in[0];
    const float* level = (const float*)d_in[1];
    float* out = (float*)d_out;
    (void)in_sizes; (void)n_in; (void)d_ws; (void)ws_size; (void)out_size;

    formant_onepass<<<BATCHES * SEGS, TPB, 0, stream>>>(audio, level, out);
}